// Round 5
// baseline (47.854 us; speedup 1.0000x reference)
//
#include <hip/hip_runtime.h>
#include <hip/hip_bf16.h>

typedef __bf16 bf16x8 __attribute__((ext_vector_type(8)));
typedef float  f32x4  __attribute__((ext_vector_type(4)));

#define NROWS 8192
#define DIM   128
#define NB    64            // 8192 / 128 row-blocks
#define JOBS_PER_MAT 2080   // 64*65/2 upper-tri incl diag
#define GRID  512           // persistent gram blocks; 64 blocks take 9 jobs, 448 take 8

__device__ __forceinline__ float waveReduceSum(float v) {
    for (int off = 32; off; off >>= 1) v += __shfl_xor(v, off, 64);
    return v;
}

__device__ __forceinline__ float fast_exp2(float x) {
    return __builtin_amdgcn_exp2f(x);
}

// async global->LDS, 16B per lane; lds dest is wave-uniform base (+lane*16 by HW)
__device__ __forceinline__ void gload16(const void* g, void* l) {
    __builtin_amdgcn_global_load_lds(
        (const __attribute__((address_space(1))) unsigned int*)(uintptr_t)g,
        (__attribute__((address_space(3))) unsigned int*)(uintptr_t)l,
        16, 0, 0);
}

__device__ __forceinline__ int tri(int b) { return b * NB - (b * (b - 1)) / 2; }

// ---------------------------------------------------------------------------
// Kernel 1: normalize rows (float4 path, 2 rows/wave), align partials, bf16
// copies. Also zeroes the gram completion counter (no extra dispatch).
// 1024 blocks x 256 threads; 8 rows per block.
// ---------------------------------------------------------------------------
__global__ __launch_bounds__(256) void prep_kernel(
    const float* __restrict__ users, const float* __restrict__ pos,
    __bf16* __restrict__ Uh, __bf16* __restrict__ Ph,
    double* __restrict__ alignPart, unsigned int* __restrict__ counter)
{
    if (blockIdx.x == 0 && threadIdx.x == 0) *counter = 0u;

    const int tid  = threadIdx.x;
    const int lane = tid & 63;
    const int w    = tid >> 6;
    const int l32  = lane & 31;
    const int half = lane >> 5;
    const int r    = blockIdx.x * 8 + w * 2 + half;

    const float4 u4 = ((const float4*)users)[r * 32 + l32];
    const float4 p4 = ((const float4*)pos )[r * 32 + l32];

    float su = u4.x*u4.x + u4.y*u4.y + u4.z*u4.z + u4.w*u4.w;
    float sp = p4.x*p4.x + p4.y*p4.y + p4.z*p4.z + p4.w*p4.w;
    for (int off = 16; off; off >>= 1) {      // half-wave reduce (per row)
        su += __shfl_xor(su, off, 64);
        sp += __shfl_xor(sp, off, 64);
    }
    const float nu  = fmaxf(sqrtf(su), 1e-12f);
    const float npp = fmaxf(sqrtf(sp), 1e-12f);

    const float ux = u4.x / nu,  uy = u4.y / nu,  uz = u4.z / nu,  uw = u4.w / nu;
    const float px = p4.x / npp, py = p4.y / npp, pz = p4.z / npp, pw = p4.w / npp;

    union { __bf16 h[4]; uint2 q; } cu, cp;
    cu.h[0] = (__bf16)ux; cu.h[1] = (__bf16)uy; cu.h[2] = (__bf16)uz; cu.h[3] = (__bf16)uw;
    cp.h[0] = (__bf16)px; cp.h[1] = (__bf16)py; cp.h[2] = (__bf16)pz; cp.h[3] = (__bf16)pw;
    ((uint2*)Uh)[r * 32 + l32] = cu.q;
    ((uint2*)Ph)[r * 32 + l32] = cp.q;

    const float dx = ux - px, dy = uy - py, dz = uz - pz, dw = uw - pw;
    float al = dx*dx + dy*dy + dz*dz + dw*dw;
    for (int off = 16; off; off >>= 1) al += __shfl_xor(al, off, 64);
    al += __shfl_xor(al, 32, 64);             // combine the two rows

    __shared__ float wsum[4];
    if (lane == 0) wsum[w] = al;
    __syncthreads();
    if (tid == 0)
        alignPart[blockIdx.x] = (double)wsum[0] + (double)wsum[1]
                              + (double)wsum[2] + (double)wsum[3];
}

// ---------------------------------------------------------------------------
// Kernel 2 (persistent): each block processes 8-9 upper-tri 128x128 tiles with
// a rolling 2-buffer pipeline (buf0 = K-half0, buf1 = K-half1 of each job).
// Stage for the next step is always issued one compute-phase before its drain.
// Last finishing block performs the final loss reduction.
// ---------------------------------------------------------------------------
__global__ __launch_bounds__(256) void gram_kernel(
    const __bf16* __restrict__ Uh, const __bf16* __restrict__ Ph,
    const double* __restrict__ alignPart, double* __restrict__ Spart,
    unsigned int* __restrict__ counter, float* __restrict__ out)
{
    __shared__ __align__(16) unsigned char smem[65536];
    __shared__ float wsum[4];
    __shared__ int lastFlag;
    __shared__ double dred[3][4];

    const int blk    = blockIdx.x;
    const int njobs  = 8 + (blk < 64);
    const int tbeg   = blk * 8 + (blk < 64 ? blk : 64);
    const int mat    = tbeg >= JOBS_PER_MAT;          // jobs never straddle matrices
    const int tt0    = tbeg - (mat ? JOBS_PER_MAT : 0);

    int bi = (int)((NB + 0.5f) - sqrtf((NB + 0.5f) * (NB + 0.5f) - 2.0f * (float)tt0));
    if (bi > 0 && tri(bi) > tt0) --bi;
    if (tri(bi + 1) <= tt0) ++bi;
    int bj = bi + (tt0 - tri(bi));

    const char* __restrict__ Xb = (const char*)(mat ? Ph : Uh);

    const int tid  = threadIdx.x;
    const int lane = tid & 63;
    const int w    = tid >> 6;

    // staging geometry: thread covers LDS rows r0+8i, chunk (lane&7); global
    // source pre-swizzled so linear gload_lds dest + XOR read = identity.
    const int r0 = w * 32 + (lane >> 3);
    const int gcOff = (((lane & 7) ^ (r0 & 7)) << 4);
    unsigned char* lA0 = smem + w * 4096;     // +p*32768 ; B region at +16384

#define STAGE(p, h, sbi, sbj)                                              \
    {                                                                      \
        const char* gA_ = Xb + (size_t)((sbi) * 128 + r0) * 256 + gcOff + (h) * 128; \
        const char* gB_ = Xb + (size_t)((sbj) * 128 + r0) * 256 + gcOff + (h) * 128; \
        unsigned char* la_ = lA0 + (p) * 32768;                            \
        _Pragma("unroll")                                                  \
        for (int i_ = 0; i_ < 4; ++i_) {                                   \
            gload16(gA_ + i_ * 2048, la_ + i_ * 1024);                     \
            gload16(gB_ + i_ * 2048, la_ + 16384 + i_ * 1024);             \
        }                                                                  \
    }

    // fragment read geometry (2x2 waves, each owns 64x64)
    const int wm = w >> 1, wn = w & 1;
    const int lr = lane & 15;
    const int lg = lane >> 4;
    const unsigned cxor = (unsigned)(lr & 7);
    const unsigned aOff = (unsigned)(wm * 64 + lr) * 128;
    const unsigned bOff = (unsigned)(wn * 64 + lr) * 128 + 16384;

    f32x4 acc[4][4];
#define ZEROACC                                                            \
    _Pragma("unroll")                                                      \
    for (int mi_ = 0; mi_ < 4; ++mi_)                                      \
        _Pragma("unroll")                                                  \
        for (int ni_ = 0; ni_ < 4; ++ni_)                                  \
            acc[mi_][ni_] = (f32x4){0.f, 0.f, 0.f, 0.f};
    ZEROACC

#define COMPUTE(p)                                                          \
    {                                                                       \
        const unsigned base = (p) * 32768;                                  \
        _Pragma("unroll")                                                   \
        for (int ks2 = 0; ks2 < 2; ++ks2) {                                 \
            const unsigned sc = (((unsigned)(ks2 * 4 + lg)) ^ cxor) << 4;   \
            bf16x8 a[4], b[4];                                              \
            _Pragma("unroll")                                               \
            for (int mi = 0; mi < 4; ++mi)                                  \
                a[mi] = *reinterpret_cast<const bf16x8*>(                   \
                    smem + base + aOff + mi * 2048 + sc);                   \
            _Pragma("unroll")                                               \
            for (int ni = 0; ni < 4; ++ni)                                  \
                b[ni] = *reinterpret_cast<const bf16x8*>(                   \
                    smem + base + bOff + ni * 2048 + sc);                   \
            _Pragma("unroll")                                               \
            for (int mi = 0; mi < 4; ++mi)                                  \
                _Pragma("unroll")                                           \
                for (int ni = 0; ni < 4; ++ni)                              \
                    acc[mi][ni] = __builtin_amdgcn_mfma_f32_16x16x32_bf16(  \
                        a[mi], b[ni], acc[mi][ni], 0, 0, 0);                \
        }                                                                   \
    }

    const float C1 = 4.0f * 1.4426950408889634f;   // 4*log2(e)
    double jobAcc = 0.0;
    int nbi = bi, nbj = bj;    // coords of the most recently staged job
    int cbi = bi, cbj = bj;    // coords of the job currently in compute

    STAGE(0, 0, nbi, nbj)
    __syncthreads();                    // buf0(job0,h0) ready

    for (int q = 0; q < njobs; ++q) {
        STAGE(1, 1, nbi, nbj)           // this job's second K-half -> buf1
        COMPUTE(0)
        __syncthreads();                // buf1 ready; buf0 reads done
        if (q + 1 < njobs) {
            if (nbj == NB - 1) { ++nbi; nbj = nbi; } else ++nbj;
            STAGE(0, 0, nbi, nbj)       // next job's first K-half -> buf0
        }
        COMPUTE(1)

        // epilogue: sum exp2(C1*dot - C1)  (== exp(-2*d^2); clamp unneeded)
        float s0 = 0.f, s1 = 0.f, s2 = 0.f, s3 = 0.f;
#pragma unroll
        for (int mi = 0; mi < 4; ++mi)
#pragma unroll
            for (int ni = 0; ni < 4; ++ni) {
                const f32x4 v = acc[mi][ni];
                s0 += fast_exp2(v[0] * C1 - C1);
                s1 += fast_exp2(v[1] * C1 - C1);
                s2 += fast_exp2(v[2] * C1 - C1);
                s3 += fast_exp2(v[3] * C1 - C1);
            }
        const float s = waveReduceSum((s0 + s1) + (s2 + s3));
        if (lane == 0) wsum[w] = s;
        __syncthreads();                // wsum ready; buf0(next job) ready
        if (tid == 0) {
            double bs = (double)wsum[0] + (double)wsum[1]
                      + (double)wsum[2] + (double)wsum[3];
            if (cbi != cbj) bs *= 2.0;  // off-diagonal tile counts twice
            jobAcc += bs;
        }
        cbi = nbi; cbj = nbj;
        ZEROACC
    }

    // ---- publish block result; last block computes the loss ----
    if (tid == 0) {
        Spart[blk] = jobAcc;
        __threadfence();
        const unsigned int old = atomicAdd(counter, 1u);
        lastFlag = (old == (unsigned int)(GRID - 1));
    }
    __syncthreads();
    if (!lastFlag) return;
    __threadfence();

    double a = 0.0, su = 0.0, sp = 0.0;
    for (int i = tid; i < 1024; i += 256) a += alignPart[i];
    for (int i = tid; i < GRID; i += 256) {
        const double v = Spart[i];
        if (i < 252) su += v; else sp += v;   // blocks 0..251 are matrix 0
    }
    for (int off = 32; off; off >>= 1) {
        a  += __shfl_xor(a,  off, 64);
        su += __shfl_xor(su, off, 64);
        sp += __shfl_xor(sp, off, 64);
    }
    if (lane == 0) { dred[0][w] = a; dred[1][w] = su; dred[2][w] = sp; }
    __syncthreads();
    if (tid == 0) {
        const double A  = dred[0][0] + dred[0][1] + dred[0][2] + dred[0][3];
        const double SU = dred[1][0] + dred[1][1] + dred[1][2] + dred[1][3];
        const double SP = dred[2][0] + dred[2][1] + dred[2][2] + dred[2][3];
        const double Nd = 8192.0;
        const double npairs = Nd * (Nd - 1.0) * 0.5;
        const double align = A / Nd;
        const double mu = (SU - Nd) * 0.5 / npairs;
        const double mp = (SP - Nd) * 0.5 / npairs;
        const double uniform = 0.25 * (log(mu) + log(mp));
        out[0] = (float)((align + uniform) / 8192.0);
    }
#undef STAGE
#undef COMPUTE
#undef ZEROACC
}

// ---------------------------------------------------------------------------
extern "C" void kernel_launch(void* const* d_in, const int* in_sizes, int n_in,
                              void* d_out, int out_size, void* d_ws, size_t ws_size,
                              hipStream_t stream)
{
    const float* users = (const float*)d_in[0];
    const float* pos   = (const float*)d_in[1];
    // d_in[2] (neg_items) intentionally unused, matching the reference.
    float* out = (float*)d_out;

    char* ws = (char*)d_ws;
    __bf16* Uh = (__bf16*)ws;                              // 2 MiB
    __bf16* Ph = (__bf16*)(ws + 2097152);                  // 2 MiB
    double* alignPart = (double*)(ws + 4194304);           // 1024 doubles
    double* Spart     = (double*)(ws + 4194304 + 8192);    // 512 doubles
    unsigned int* counter = (unsigned int*)(ws + 4194304 + 12288);

    hipLaunchKernelGGL(prep_kernel, dim3(1024), dim3(256), 0, stream,
                       users, pos, Uh, Ph, alignPart, counter);
    hipLaunchKernelGGL(gram_kernel, dim3(GRID), dim3(256), 0, stream,
                       Uh, Ph, alignPart, Spart, counter, out);
}